// Round 21
// baseline (152.262 us; speedup 1.0000x reference)
//
#include <hip/hip_runtime.h>
#include <hip/hip_bf16.h>

#define N_NODES 50000
#define N_EDGES 800000
#define F_IN    256
#define C_DIM   64
#define HC      128   // H*C
#define NPG     6250  // nodes per XCD group (N/8)
#define NBB     32    // build blocks per group
#define NBLK    196   // scan blocks
#define XW_BLOCKS   3125
#define HIST_BLOCKS 256

typedef __attribute__((ext_vector_type(8))) short bf16x8;
typedef __attribute__((ext_vector_type(4))) float f32x4;

// ---------------- workspace layout (bytes) ----------------
static constexpr size_t OFF_HBF   = 0;           // u32  h packed  [N][64] = 12.8 MB
static constexpr size_t OFF_AB    = 25600000;    // u32  ab packed [N][64] = 12.8 MB
static constexpr size_t OFF_AS    = 38400000;    // f32 [N][2]
static constexpr size_t OFF_AD    = 38800000;
static constexpr size_t OFF_OFFS  = 39200000;    // i32 N+1
static constexpr size_t OFF_TOT   = 39400064;    // i32 N
static constexpr size_t OFF_PART  = 39800064;
static constexpr size_t OFF_CSR2  = 39801088;    // int2 [E] = 6.4 MB
static constexpr size_t OFF_WT    = 46201088;    // bf16 Wt   [128][256]
static constexpr size_t OFF_FC1T  = 46266624;    // bf16 fc1t [128][128]
static constexpr size_t OFF_SCALE = 46299392;    // f32 [128]
static constexpr size_t OFF_CC    = 46299904;    // f32 [128]
static constexpr size_t OFF_FC2M  = 46300416;    // bf16 fc2m [2][64][8]
static constexpr size_t OFF_BCNT  = 46302464;    // i32 [256][6250] = 6.4 MB
static constexpr size_t OFF_BASE  = 52702464;    // i32 [256][6250] = 6.4 MB

__device__ __forceinline__ float2 bf2(unsigned u) {
    float2 r;
    r.x = __uint_as_float(u << 16);
    r.y = __uint_as_float(u & 0xffff0000u);
    return r;
}
__device__ __forceinline__ unsigned short f2bf(float f) {
    unsigned u = __float_as_uint(f);
    return (unsigned short)((u + 0x7fffu + ((u >> 16) & 1u)) >> 16);  // RNE
}
__device__ __forceinline__ short f2bf_s(float f) {
    __hip_bfloat16 h = __float2bfloat16(f);
    return *reinterpret_cast<short*>(&h);
}
// packed-channel mapping: word q of a row holds channels (c0(q), c0(q)+16),
// c0(q) = 32*(q>>4) + (q&15)

// ---------------- prep (runs FIRST: produces Wt/fc1t/fc2m/scale/cc) ----------------
__global__ __launch_bounds__(256) void k_prep(const float* __restrict__ W,
                                              const float* __restrict__ fc1,
                                              const float* __restrict__ fc1_b,
                                              const float* __restrict__ gamma,
                                              const float* __restrict__ beta,
                                              const float* __restrict__ mean,
                                              const float* __restrict__ var,
                                              const float* __restrict__ fc2_w,
                                              unsigned short* __restrict__ Wt,
                                              unsigned short* __restrict__ fc1t,
                                              float* __restrict__ scale,
                                              float* __restrict__ cc,
                                              unsigned short* __restrict__ fc2m) {
    int id = blockIdx.x * 256 + threadIdx.x;
    if (id < 32768) {
        int n = id >> 8, k = id & 255;
        Wt[id] = f2bf(W[k * HC + n]);
    }
    int id2 = id - 32768;
    if (id2 >= 0 && id2 < 16384) {
        int j = id2 >> 7, q = id2 & 127;
        int L = q >> 1, b = q & 1;
        int kch = 32 * (L >> 4) + (L & 15) + 16 * b;
        float v = (j < 64) ? fc1[kch * 64 + j] : fc1[(128 + kch) * 64 + (j - 64)];
        fc1t[id2] = f2bf(v);
    }
    int id3 = id - (32768 + 16384);
    if (id3 >= 0 && id3 < 128) {
        int jj = id3 & 63;
        float s = gamma[jj] * rsqrtf(var[jj] + 1e-5f);
        scale[id3] = s;
        cc[id3] = (id3 < 64) ? 0.f : (fc1_b[jj] - mean[jj]) * s + beta[jj];
    }
    int id4 = id - (32768 + 16384 + 128);
    if (id4 >= 0 && id4 < 1024) {
        int kk = id4 >> 9, rem = id4 & 511;
        int lane = rem >> 3, j = rem & 7;
        int q  = kk * 16 + (lane >> 4) * 4 + (j >> 1);
        int ch = 32 * (q >> 4) + (q & 15) + 16 * (j & 1);
        int col = lane & 15;
        float v = (col < 3) ? fc2_w[ch * 3 + col] : 0.f;
        fc2m[id4] = f2bf(v);
    }
}

// ---------------- k_front: fused hist (0..255, first) | xw-GEMM (256..3380) ----------------
__global__ __launch_bounds__(256, 4) void k_front(const float* __restrict__ x,
                                                  const unsigned short* __restrict__ Wt,
                                                  const float* __restrict__ att_src,
                                                  const float* __restrict__ att_dst,
                                                  unsigned* __restrict__ h_p,
                                                  float* __restrict__ as_,
                                                  float* __restrict__ ad_,
                                                  const int* __restrict__ dst,
                                                  int* __restrict__ bcnt) {
    __shared__ int smem[6464];   // 25856 B: hist uses 25 KB, xw uses 16.6 KB
    const int t = threadIdx.x;

    if (blockIdx.x < HIST_BLOCKS) {
        int* hist = smem;
        const int bid = blockIdx.x;
        const int g  = bid & 7;
        const int bi = bid >> 3;
        const int lo = g * NPG, hi = lo + NPG;
        for (int j = t; j < NPG; j += 256) hist[j] = 0;
        __syncthreads();
        const int4* d4 = (const int4*)dst + bi * 6250;
#pragma unroll 1
        for (int it = 0; it < 25; ++it) {
            int idx = it * 256 + t;
            if (idx < 6250) {
                int4 d = d4[idx];
                if (d.x >= lo && d.x < hi) atomicAdd(&hist[d.x - lo], 1);
                if (d.y >= lo && d.y < hi) atomicAdd(&hist[d.y - lo], 1);
                if (d.z >= lo && d.z < hi) atomicAdd(&hist[d.z - lo], 1);
                if (d.w >= lo && d.w < hi) atomicAdd(&hist[d.w - lo], 1);
            }
        }
        __syncthreads();
        int* row = bcnt + (size_t)(g * NBB + bi) * NPG;
        for (int j = t; j < NPG; j += 256) row[j] = hist[j];
        return;
    }

    // ---- xw-GEMM branch ----
    float* xs  = (float*)smem;
    float* sAs = (float*)(smem + 4096);
    float* sAd = sAs + 32;
    const int v    = t >> 6;
    const int lane = t & 63;
    const int c16  = lane & 15;
    const int kg   = lane >> 4;
    const int r0   = (blockIdx.x - HIST_BLOCKS) * 16;
    if (t < 32) { sAs[t] = 0.f; sAd[t] = 0.f; }
    {
        const float4* xsrc = (const float4*)(x + (size_t)r0 * F_IN);
        float4* xsl = (float4*)xs;
#pragma unroll
        for (int it = 0; it < 4; ++it) {
            int cidx = it * 256 + t;
            int rl = cidx >> 6, j = cidx & 63;
            float4 val = xsrc[cidx];
            xsl[rl * 64 + (j ^ rl)] = val;
        }
    }
    const int cf0 = 2 * v, cf1 = 2 * v + 1;
    bf16x8 wf0[8], wf1[8];
#pragma unroll
    for (int kk = 0; kk < 8; ++kk) {
        wf0[kk] = *(const bf16x8*)(Wt + (size_t)(cf0 * 16 + c16) * 256 + kk * 32 + kg * 8);
        wf1[kk] = *(const bf16x8*)(Wt + (size_t)(cf1 * 16 + c16) * 256 + kk * 32 + kg * 8);
    }
    __syncthreads();

    f32x4 acc0 = {}, acc1 = {};
#pragma unroll
    for (int kk = 0; kk < 8; ++kk) {
        int j0 = kk * 8 + kg * 2;
        float4 a0 = *(const float4*)(xs + (size_t)(c16 * 64 + (j0 ^ c16)) * 4);
        float4 a1 = *(const float4*)(xs + (size_t)(c16 * 64 + ((j0 + 1) ^ c16)) * 4);
        float fv[8] = {a0.x, a0.y, a0.z, a0.w, a1.x, a1.y, a1.z, a1.w};
        bf16x8 ahi, alo;
#pragma unroll
        for (int q = 0; q < 8; ++q) {
            unsigned u = __float_as_uint(fv[q]);
            float hval = __uint_as_float(u & 0xffff0000u);
            float d = fv[q] - hval;
            ahi[q] = (short)(u >> 16);
            alo[q] = (short)(__float_as_uint(d) >> 16);
        }
        acc0 = __builtin_amdgcn_mfma_f32_16x16x32_bf16(alo, wf0[kk], acc0, 0, 0, 0);
        acc0 = __builtin_amdgcn_mfma_f32_16x16x32_bf16(ahi, wf0[kk], acc0, 0, 0, 0);
        acc1 = __builtin_amdgcn_mfma_f32_16x16x32_bf16(alo, wf1[kk], acc1, 0, 0, 0);
        acc1 = __builtin_amdgcn_mfma_f32_16x16x32_bf16(ahi, wf1[kk], acc1, 0, 0, 0);
    }
#pragma unroll
    for (int i = 0; i < 4; ++i) {
        int row = r0 + kg * 4 + i;
        unsigned pu = (unsigned)f2bf(acc0[i]) | ((unsigned)f2bf(acc1[i]) << 16);
        h_p[(size_t)row * 64 + v * 16 + c16] = pu;
    }
    float ws0 = att_src[cf0 * 16 + c16], ws1 = att_src[cf1 * 16 + c16];
    float wd0 = att_dst[cf0 * 16 + c16], wd1 = att_dst[cf1 * 16 + c16];
    float pas[4], pad[4];
#pragma unroll
    for (int i = 0; i < 4; ++i) {
        pas[i] = acc0[i] * ws0 + acc1[i] * ws1;
        pad[i] = acc0[i] * wd0 + acc1[i] * wd1;
    }
#pragma unroll
    for (int m = 1; m < 16; m <<= 1) {
#pragma unroll
        for (int i = 0; i < 4; ++i) {
            pas[i] += __shfl_xor(pas[i], m, 64);
            pad[i] += __shfl_xor(pad[i], m, 64);
        }
    }
    const int head = v >> 1;
    if (c16 == 0) {
#pragma unroll
        for (int i = 0; i < 4; ++i) {
            atomicAdd(&sAs[(kg * 4 + i) * 2 + head], pas[i]);
            atomicAdd(&sAd[(kg * 4 + i) * 2 + head], pad[i]);
        }
    }
    __syncthreads();
    if (t < 32) {
        int row = t >> 1, hd = t & 1;
        as_[(r0 + row) * 2 + hd] = sAs[row * 2 + hd];
        ad_[(r0 + row) * 2 + hd] = sAd[row * 2 + hd];
    }
}

// ---------------- merged: per-node degree + block partial sum ----------------
__global__ void k_tot_part(const int* __restrict__ bcnt, int* __restrict__ tot,
                           int* __restrict__ part) {
    __shared__ int sd[256];
    int n = blockIdx.x * 256 + threadIdx.x;
    int s = 0;
    if (n < N_NODES) {
        int g = n / NPG, ln = n - g * NPG;
        const int* col = bcnt + (size_t)g * NBB * NPG + ln;
#pragma unroll
        for (int bi = 0; bi < NBB; ++bi) s += col[bi * NPG];
        tot[n] = s;
    }
    sd[threadIdx.x] = s;
    __syncthreads();
    for (int off = 128; off > 0; off >>= 1) {
        if (threadIdx.x < off) sd[threadIdx.x] += sd[threadIdx.x + off];
        __syncthreads();
    }
    if (threadIdx.x == 0) part[blockIdx.x] = sd[0];
}

// merged: base reduction + local scan + per-slice base expansion
__global__ void k_scan_base(const int* __restrict__ tot, const int* __restrict__ part,
                            const int* __restrict__ bcnt, int* __restrict__ offs,
                            int* __restrict__ base) {
    __shared__ int sp[256];
    __shared__ int sd[256];
    const int t = threadIdx.x;
    int pv = (t < NBLK && t < (int)blockIdx.x) ? part[t] : 0;
    sp[t] = pv;
    __syncthreads();
    for (int off = 128; off > 0; off >>= 1) {
        if (t < off) sp[t] += sp[t + off];
        __syncthreads();
    }
    const int bb = sp[0];
    __syncthreads();
    int i = blockIdx.x * 256 + t;
    int v = (i < N_NODES) ? tot[i] : 0;
    sd[t] = v;
    __syncthreads();
    for (int off = 1; off < 256; off <<= 1) {
        int u = (t >= off) ? sd[t - off] : 0;
        __syncthreads();
        sd[t] += u;
        __syncthreads();
    }
    if (i < N_NODES) {
        int o = bb + sd[t] - v;
        offs[i] = o;
        if (i == N_NODES - 1) offs[N_NODES] = o + v;
        int g = i / NPG, ln = i - g * NPG;
        const int* col = bcnt + (size_t)g * NBB * NPG + ln;
        int* bcol = base + (size_t)g * NBB * NPG + ln;
        int run = o;
#pragma unroll
        for (int bi = 0; bi < NBB; ++bi) {
            bcol[bi * NPG] = run;
            run += col[bi * NPG];
        }
    }
}

// scatter via LDS counters — no global atomics
__global__ __launch_bounds__(256) void k_scatter(const int* __restrict__ src,
                                                 const int* __restrict__ dst,
                                                 const int* __restrict__ base,
                                                 int2* __restrict__ csr2) {
    __shared__ int cnt[NPG];
    const int g  = blockIdx.x & 7;
    const int bi = blockIdx.x >> 3;
    const int lo = g * NPG, hi = lo + NPG;
    const int* brow = base + (size_t)(g * NBB + bi) * NPG;
    for (int j = threadIdx.x; j < NPG; j += 256) cnt[j] = brow[j];
    __syncthreads();
    const int4* d4 = (const int4*)dst + bi * 6250;
    const int4* s4 = (const int4*)src + bi * 6250;
    const int ebase = bi * 25000;
#pragma unroll 1
    for (int it = 0; it < 25; ++it) {
        int idx = it * 256 + threadIdx.x;
        if (idx < 6250) {
            int4 d = d4[idx];
            int4 s = s4[idx];
            int e = ebase + idx * 4;
            if (d.x >= lo && d.x < hi) { int p = atomicAdd(&cnt[d.x - lo], 1); csr2[p] = make_int2(s.x, e);     }
            if (d.y >= lo && d.y < hi) { int p = atomicAdd(&cnt[d.y - lo], 1); csr2[p] = make_int2(s.y, e + 1); }
            if (d.z >= lo && d.z < hi) { int p = atomicAdd(&cnt[d.z - lo], 1); csr2[p] = make_int2(s.z, e + 2); }
            if (d.w >= lo && d.w < hi) { int p = atomicAdd(&cnt[d.w - lo], 1); csr2[p] = make_int2(s.w, e + 3); }
        }
    }
}

// ---------------- k_agg_uv: work-queue aggregate + fused uv GEMM via LDS ----------------
// block = 16 nodes; waves pop nodes from an LDS queue (balances degree variance);
// node j lands in LDS row j; barrier; cf-split uv MFMA writes ab.
__global__ __launch_bounds__(256) void k_agg_uv(const unsigned* __restrict__ h_p,
                                                const float* __restrict__ as_,
                                                const float* __restrict__ ad_,
                                                const int* __restrict__ offs,
                                                const int2* __restrict__ csr2,
                                                const float* __restrict__ conv_bias,
                                                const unsigned short* __restrict__ fc1t,
                                                const float* __restrict__ scale,
                                                const float* __restrict__ cc,
                                                unsigned* __restrict__ ab_p) {
    __shared__ unsigned lds_h2[16 * 68];   // 4352 B
    __shared__ int next_node;
    const int t    = threadIdx.x;
    const int lane = t & 63;
    const int ql   = lane & 15;
    const int q    = lane >> 4;
    const int hd   = ql >> 3;
    const int nbase = blockIdx.x * 16;
    const uint4* h4 = (const uint4*)h_p;
    if (t == 0) next_node = 0;
    __syncthreads();

#pragma unroll 1
    for (;;) {
        int j = 0;
        if (lane == 0) j = atomicAdd(&next_node, 1);
        j = __shfl(j, 0, 64);
        if (j >= 16) break;
        const int n = nbase + j;
        const float adn = ad_[n * 2 + hd];
        float a[8] = {};
        float accw = 0.f;
        const int beg = offs[n], end = offs[n + 1];
        int i = beg + q;
        for (; i + 4 < end; i += 8) {
            int s0 = csr2[i].x;
            int s1 = csr2[i + 4].x;
            uint4 u0 = h4[(unsigned)(s0 * 16 + ql)];
            uint4 u1 = h4[(unsigned)(s1 * 16 + ql)];
            float l0 = as_[s0 * 2 + hd] + adn;
            float l1 = as_[s1 * 2 + hd] + adn;
            l0 = fmaxf(l0, 0.2f * l0);
            l1 = fmaxf(l1, 0.2f * l1);
            float w0 = __expf(l0), w1 = __expf(l1);
            float2 tt;
            tt = bf2(u0.x); a[0] += w0 * tt.x; a[1] += w0 * tt.y;
            tt = bf2(u0.y); a[2] += w0 * tt.x; a[3] += w0 * tt.y;
            tt = bf2(u0.z); a[4] += w0 * tt.x; a[5] += w0 * tt.y;
            tt = bf2(u0.w); a[6] += w0 * tt.x; a[7] += w0 * tt.y;
            tt = bf2(u1.x); a[0] += w1 * tt.x; a[1] += w1 * tt.y;
            tt = bf2(u1.y); a[2] += w1 * tt.x; a[3] += w1 * tt.y;
            tt = bf2(u1.z); a[4] += w1 * tt.x; a[5] += w1 * tt.y;
            tt = bf2(u1.w); a[6] += w1 * tt.x; a[7] += w1 * tt.y;
            accw += w0 + w1;
        }
        if (i < end) {
            int s0 = csr2[i].x;
            uint4 u0 = h4[(unsigned)(s0 * 16 + ql)];
            float l0 = as_[s0 * 2 + hd] + adn;
            l0 = fmaxf(l0, 0.2f * l0);
            float w0 = __expf(l0);
            float2 tt;
            tt = bf2(u0.x); a[0] += w0 * tt.x; a[1] += w0 * tt.y;
            tt = bf2(u0.y); a[2] += w0 * tt.x; a[3] += w0 * tt.y;
            tt = bf2(u0.z); a[4] += w0 * tt.x; a[5] += w0 * tt.y;
            tt = bf2(u0.w); a[6] += w0 * tt.x; a[7] += w0 * tt.y;
            accw += w0;
        }
#pragma unroll
        for (int m = 16; m < 64; m <<= 1) {
#pragma unroll
            for (int jj = 0; jj < 8; ++jj) a[jj] += __shfl_xor(a[jj], m, 64);
            accw += __shfl_xor(accw, m, 64);
        }
        if (q == 0) {
            float es = as_[n * 2 + hd] + adn;   // self-loop
            es = fmaxf(es, 0.2f * es);
            float wsl = __expf(es);
            uint4 un = h4[(unsigned)(n * 16 + ql)];
            float2 tt;
            tt = bf2(un.x); a[0] += wsl * tt.x; a[1] += wsl * tt.y;
            tt = bf2(un.y); a[2] += wsl * tt.x; a[3] += wsl * tt.y;
            tt = bf2(un.z); a[4] += wsl * tt.x; a[5] += wsl * tt.y;
            tt = bf2(un.w); a[6] += wsl * tt.x; a[7] += wsl * tt.y;
            accw += wsl;
            float rinv = 1.f / accw;
            unsigned pw[4];
#pragma unroll
            for (int jj = 0; jj < 4; ++jj) {
                int w = 4 * ql + jj;
                int c = 32 * (w >> 4) + (w & 15);
                float o0 = a[2 * jj] * rinv + conv_bias[c];
                float o1 = a[2 * jj + 1] * rinv + conv_bias[c + 16];
                o0 = fmaxf(o0, 0.01f * o0);
                o1 = fmaxf(o1, 0.01f * o1);
                pw[jj] = (unsigned)f2bf(o0) | ((unsigned)f2bf(o1) << 16);
            }
            *(uint4*)&lds_h2[j * 68 + ql * 4] = make_uint4(pw[0], pw[1], pw[2], pw[3]);
        }
    }
    __syncthreads();

    // ---- fused uv GEMM: wave v owns cf pair {2v, 2v+1}, A from LDS ----
    const int v   = t >> 6;
    const int c16 = lane & 15;
    const int kg  = lane >> 4;
    const int cf0 = 2 * v, cf1 = 2 * v + 1;
    bf16x8 af[4];
#pragma unroll
    for (int kk = 0; kk < 4; ++kk)
        af[kk] = *(const bf16x8*)&lds_h2[c16 * 68 + kk * 16 + kg * 4];
    f32x4 acc0 = {}, acc1 = {};
#pragma unroll
    for (int kk = 0; kk < 4; ++kk) {
        bf16x8 b0 = *(const bf16x8*)(fc1t + (size_t)(cf0 * 16 + c16) * HC + kk * 32 + kg * 8);
        bf16x8 b1 = *(const bf16x8*)(fc1t + (size_t)(cf1 * 16 + c16) * HC + kk * 32 + kg * 8);
        acc0 = __builtin_amdgcn_mfma_f32_16x16x32_bf16(af[kk], b0, acc0, 0, 0, 0);
        acc1 = __builtin_amdgcn_mfma_f32_16x16x32_bf16(af[kk], b1, acc1, 0, 0, 0);
    }
    const int j0 = cf0 * 16 + c16, j1 = j0 + 16;
    const float s0 = scale[j0], s1 = scale[j1];
    const float q0 = cc[j0],    q1 = cc[j1];
#pragma unroll
    for (int i = 0; i < 4; ++i) {
        int row = nbase + kg * 4 + i;
        unsigned pu = (unsigned)f2bf(acc0[i] * s0 + q0)
                    | ((unsigned)f2bf(acc1[i] * s1 + q1) << 16);
        ab_p[(size_t)row * 64 + v * 16 + c16] = pu;
    }
}

// ---------------- k_edge: MFMA tail ----------------
__device__ __forceinline__ void mk_afrag(uint4 ua, const float* bb, bf16x8& ap) {
    float2 t; float z;
    t = bf2(ua.x);
    z = t.x + bb[0]; z = fmaxf(z, 0.01f * z); ap[0] = f2bf_s(z);
    z = t.y + bb[1]; z = fmaxf(z, 0.01f * z); ap[1] = f2bf_s(z);
    t = bf2(ua.y);
    z = t.x + bb[2]; z = fmaxf(z, 0.01f * z); ap[2] = f2bf_s(z);
    z = t.y + bb[3]; z = fmaxf(z, 0.01f * z); ap[3] = f2bf_s(z);
    t = bf2(ua.z);
    z = t.x + bb[4]; z = fmaxf(z, 0.01f * z); ap[4] = f2bf_s(z);
    z = t.y + bb[5]; z = fmaxf(z, 0.01f * z); ap[5] = f2bf_s(z);
    t = bf2(ua.w);
    z = t.x + bb[6]; z = fmaxf(z, 0.01f * z); ap[6] = f2bf_s(z);
    z = t.y + bb[7]; z = fmaxf(z, 0.01f * z); ap[7] = f2bf_s(z);
}

__global__ __launch_bounds__(256) void k_edge(const int* __restrict__ offs,
                                              const int2* __restrict__ csr2,
                                              const unsigned* __restrict__ ab_p,
                                              const unsigned short* __restrict__ fc2m,
                                              const float* __restrict__ fc2_b,
                                              float* __restrict__ out) {
    const int n    = blockIdx.x * 4 + (threadIdx.x >> 6);
    const int lane = threadIdx.x & 63;
    const int c16  = lane & 15;
    const int kg   = lane >> 4;
    bf16x8 bfr0 = *(const bf16x8*)(fc2m + (size_t)lane * 8);
    bf16x8 bfr1 = *(const bf16x8*)(fc2m + (size_t)(64 + lane) * 8);
    const uint4* abv = (const uint4*)ab_p;
    uint4 ub0 = abv[(unsigned)(n * 16 + 8 + kg)];
    uint4 ub1 = abv[(unsigned)(n * 16 + 12 + kg)];
    float bb0[8], bb1[8];
    {
        float2 t;
        t = bf2(ub0.x); bb0[0] = t.x; bb0[1] = t.y;
        t = bf2(ub0.y); bb0[2] = t.x; bb0[3] = t.y;
        t = bf2(ub0.z); bb0[4] = t.x; bb0[5] = t.y;
        t = bf2(ub0.w); bb0[6] = t.x; bb0[7] = t.y;
        t = bf2(ub1.x); bb1[0] = t.x; bb1[1] = t.y;
        t = bf2(ub1.y); bb1[2] = t.x; bb1[3] = t.y;
        t = bf2(ub1.z); bb1[4] = t.x; bb1[5] = t.y;
        t = bf2(ub1.w); bb1[6] = t.x; bb1[7] = t.y;
    }
    const float ob = (c16 < 3) ? fc2_b[c16] : 0.f;
    const int beg = offs[n], end = offs[n + 1];
    for (int base = beg; base < end; base += 16) {
        int slot = base + c16;
        int2 ce = (slot < end) ? csr2[slot] : make_int2(0, 0);
        uint4 ua0 = abv[(unsigned)(ce.x * 16 + kg)];
        uint4 ua1 = abv[(unsigned)(ce.x * 16 + 4 + kg)];
        bf16x8 ap0, ap1;
        mk_afrag(ua0, bb0, ap0);
        mk_afrag(ua1, bb1, ap1);
        f32x4 acc = {};
        acc = __builtin_amdgcn_mfma_f32_16x16x32_bf16(ap0, bfr0, acc, 0, 0, 0);
        acc = __builtin_amdgcn_mfma_f32_16x16x32_bf16(ap1, bfr1, acc, 0, 0, 0);
#pragma unroll
        for (int i = 0; i < 4; ++i) {
            int eid = __shfl(ce.y, kg * 4 + i, 64);
            if (c16 < 3 && (base + kg * 4 + i) < end)
                out[(size_t)eid * 3 + c16] = acc[i] + ob;
        }
    }
}

extern "C" void kernel_launch(void* const* d_in, const int* in_sizes, int n_in,
                              void* d_out, int out_size, void* d_ws, size_t ws_size,
                              hipStream_t stream) {
    const float* x        = (const float*)d_in[0];
    const int*   ei       = (const int*)d_in[1];
    const float* W        = (const float*)d_in[2];
    const float* att_src  = (const float*)d_in[3];
    const float* att_dst  = (const float*)d_in[4];
    const float* conv_b   = (const float*)d_in[5];
    const float* fc1_w    = (const float*)d_in[6];
    const float* fc1_b    = (const float*)d_in[7];
    const float* gamma    = (const float*)d_in[8];
    const float* beta     = (const float*)d_in[9];
    const float* mean     = (const float*)d_in[10];
    const float* var      = (const float*)d_in[11];
    const float* fc2_w    = (const float*)d_in[12];
    const float* fc2_b    = (const float*)d_in[13];
    float*       out      = (float*)d_out;
    char*        ws       = (char*)d_ws;

    const int* src = ei;
    const int* dst = ei + N_EDGES;

    unsigned*       h_p   = (unsigned*)(ws + OFF_HBF);
    unsigned*       ab_p  = (unsigned*)(ws + OFF_AB);
    float*          as_   = (float*)(ws + OFF_AS);
    float*          ad_   = (float*)(ws + OFF_AD);
    int*            offs  = (int*)(ws + OFF_OFFS);
    int*            tot   = (int*)(ws + OFF_TOT);
    int*            part  = (int*)(ws + OFF_PART);
    int2*           csr2  = (int2*)(ws + OFF_CSR2);
    unsigned short* Wt    = (unsigned short*)(ws + OFF_WT);
    unsigned short* fc1t  = (unsigned short*)(ws + OFF_FC1T);
    float*          scale = (float*)(ws + OFF_SCALE);
    float*          cc    = (float*)(ws + OFF_CC);
    unsigned short* fc2m  = (unsigned short*)(ws + OFF_FC2M);
    int*            bcnt  = (int*)(ws + OFF_BCNT);
    int*            base  = (int*)(ws + OFF_BASE);

    // prep first (produces Wt consumed by k_front's xw branch)
    k_prep<<<235, 256, 0, stream>>>(W, fc1_w, fc1_b, gamma, beta, mean, var, fc2_w,
                                    Wt, fc1t, scale, cc, fc2m);

    // fused histogram (blocks 0..255, launched first) + xw-GEMM
    k_front<<<HIST_BLOCKS + XW_BLOCKS, 256, 0, stream>>>(x, Wt, att_src, att_dst,
                                                         h_p, as_, ad_, dst, bcnt);

    // CSR finish
    k_tot_part <<<NBLK, 256, 0, stream>>>(bcnt, tot, part);
    k_scan_base<<<NBLK, 256, 0, stream>>>(tot, part, bcnt, offs, base);
    k_scatter  <<<8 * NBB, 256, 0, stream>>>(src, dst, base, csr2);

    // aggregate + fused uv GEMM, then edge tail
    k_agg_uv<<<N_NODES / 16, 256, 0, stream>>>(h_p, as_, ad_, offs, csr2, conv_b,
                                               fc1t, scale, cc, ab_p);
    k_edge  <<<N_NODES / 4, 256, 0, stream>>>(offs, csr2, ab_p, fc2m, fc2_b, out);
}

// Round 22
// 150.611 us; speedup vs baseline: 1.0110x; 1.0110x over previous
//
#include <hip/hip_runtime.h>
#include <hip/hip_bf16.h>

#define N_NODES 50000
#define N_EDGES 800000
#define F_IN    256
#define C_DIM   64
#define HC      128   // H*C
#define NPG     6250  // nodes per XCD group (N/8)
#define NBB     32    // build blocks per group
#define NBLK    196   // scan blocks
#define XW_BLOCKS   3125
#define HIST_BLOCKS 256

typedef __attribute__((ext_vector_type(8))) short bf16x8;
typedef __attribute__((ext_vector_type(4))) float f32x4;

// ---------------- workspace layout (bytes) ----------------
static constexpr size_t OFF_HBF   = 0;           // u32  h packed  [N][64] = 12.8 MB
static constexpr size_t OFF_AB    = 25600000;    // u32  ab packed [N][64] = 12.8 MB
static constexpr size_t OFF_AS    = 38400000;    // f32 [N][2]
static constexpr size_t OFF_AD    = 38800000;
static constexpr size_t OFF_OFFS  = 39200000;    // i32 N+1
static constexpr size_t OFF_TOT   = 39400064;    // i32 N
static constexpr size_t OFF_PART  = 39800064;
static constexpr size_t OFF_CSR   = 39801088;    // i32 [E] (src only) = 3.2 MB
static constexpr size_t OFF_WT    = 46201088;    // bf16 Wt   [128][256]
static constexpr size_t OFF_FC1T  = 46266624;    // bf16 fc1t [128][128]
static constexpr size_t OFF_SCALE = 46299392;    // f32 [128]
static constexpr size_t OFF_CC    = 46299904;    // f32 [128]
static constexpr size_t OFF_FC2M  = 46300416;    // bf16 fc2m [2][64][8]
static constexpr size_t OFF_BCNT  = 46302464;    // i32 [256][6250] = 6.4 MB
static constexpr size_t OFF_BASE  = 52702464;    // i32 [256][6250] = 6.4 MB

__device__ __forceinline__ float2 bf2(unsigned u) {
    float2 r;
    r.x = __uint_as_float(u << 16);
    r.y = __uint_as_float(u & 0xffff0000u);
    return r;
}
__device__ __forceinline__ unsigned short f2bf(float f) {
    unsigned u = __float_as_uint(f);
    return (unsigned short)((u + 0x7fffu + ((u >> 16) & 1u)) >> 16);  // RNE
}
__device__ __forceinline__ short f2bf_s(float f) {
    __hip_bfloat16 h = __float2bfloat16(f);
    return *reinterpret_cast<short*>(&h);
}
// packed-channel mapping: word q of a row holds channels (c0(q), c0(q)+16),
// c0(q) = 32*(q>>4) + (q&15)

// ---------------- prep (runs FIRST: produces Wt/fc1t/fc2m/scale/cc) ----------------
__global__ __launch_bounds__(256) void k_prep(const float* __restrict__ W,
                                              const float* __restrict__ fc1,
                                              const float* __restrict__ fc1_b,
                                              const float* __restrict__ gamma,
                                              const float* __restrict__ beta,
                                              const float* __restrict__ mean,
                                              const float* __restrict__ var,
                                              const float* __restrict__ fc2_w,
                                              unsigned short* __restrict__ Wt,
                                              unsigned short* __restrict__ fc1t,
                                              float* __restrict__ scale,
                                              float* __restrict__ cc,
                                              unsigned short* __restrict__ fc2m) {
    int id = blockIdx.x * 256 + threadIdx.x;
    if (id < 32768) {
        int n = id >> 8, k = id & 255;
        Wt[id] = f2bf(W[k * HC + n]);
    }
    int id2 = id - 32768;
    if (id2 >= 0 && id2 < 16384) {
        int j = id2 >> 7, q = id2 & 127;
        int L = q >> 1, b = q & 1;
        int kch = 32 * (L >> 4) + (L & 15) + 16 * b;
        float v = (j < 64) ? fc1[kch * 64 + j] : fc1[(128 + kch) * 64 + (j - 64)];
        fc1t[id2] = f2bf(v);
    }
    int id3 = id - (32768 + 16384);
    if (id3 >= 0 && id3 < 128) {
        int jj = id3 & 63;
        float s = gamma[jj] * rsqrtf(var[jj] + 1e-5f);
        scale[id3] = s;
        cc[id3] = (id3 < 64) ? 0.f : (fc1_b[jj] - mean[jj]) * s + beta[jj];
    }
    int id4 = id - (32768 + 16384 + 128);
    if (id4 >= 0 && id4 < 1024) {
        int kk = id4 >> 9, rem = id4 & 511;
        int lane = rem >> 3, j = rem & 7;
        int q  = kk * 16 + (lane >> 4) * 4 + (j >> 1);
        int ch = 32 * (q >> 4) + (q & 15) + 16 * (j & 1);
        int col = lane & 15;
        float v = (col < 3) ? fc2_w[ch * 3 + col] : 0.f;
        fc2m[id4] = f2bf(v);
    }
}

// ---------------- k_front: fused hist (0..255, first) | xw-GEMM (256..3380) ----------------
__global__ __launch_bounds__(256, 4) void k_front(const float* __restrict__ x,
                                                  const unsigned short* __restrict__ Wt,
                                                  const float* __restrict__ att_src,
                                                  const float* __restrict__ att_dst,
                                                  unsigned* __restrict__ h_p,
                                                  float* __restrict__ as_,
                                                  float* __restrict__ ad_,
                                                  const int* __restrict__ dst,
                                                  int* __restrict__ bcnt) {
    __shared__ int smem[6464];   // 25856 B: hist uses 25 KB, xw uses 16.6 KB
    const int t = threadIdx.x;

    if (blockIdx.x < HIST_BLOCKS) {
        int* hist = smem;
        const int bid = blockIdx.x;
        const int g  = bid & 7;
        const int bi = bid >> 3;
        const int lo = g * NPG, hi = lo + NPG;
        for (int j = t; j < NPG; j += 256) hist[j] = 0;
        __syncthreads();
        const int4* d4 = (const int4*)dst + bi * 6250;
#pragma unroll 1
        for (int it = 0; it < 25; ++it) {
            int idx = it * 256 + t;
            if (idx < 6250) {
                int4 d = d4[idx];
                if (d.x >= lo && d.x < hi) atomicAdd(&hist[d.x - lo], 1);
                if (d.y >= lo && d.y < hi) atomicAdd(&hist[d.y - lo], 1);
                if (d.z >= lo && d.z < hi) atomicAdd(&hist[d.z - lo], 1);
                if (d.w >= lo && d.w < hi) atomicAdd(&hist[d.w - lo], 1);
            }
        }
        __syncthreads();
        int* row = bcnt + (size_t)(g * NBB + bi) * NPG;
        for (int j = t; j < NPG; j += 256) row[j] = hist[j];
        return;
    }

    // ---- xw-GEMM branch ----
    float* xs  = (float*)smem;
    float* sAs = (float*)(smem + 4096);
    float* sAd = sAs + 32;
    const int v    = t >> 6;
    const int lane = t & 63;
    const int c16  = lane & 15;
    const int kg   = lane >> 4;
    const int r0   = (blockIdx.x - HIST_BLOCKS) * 16;
    if (t < 32) { sAs[t] = 0.f; sAd[t] = 0.f; }
    {
        const float4* xsrc = (const float4*)(x + (size_t)r0 * F_IN);
        float4* xsl = (float4*)xs;
#pragma unroll
        for (int it = 0; it < 4; ++it) {
            int cidx = it * 256 + t;
            int rl = cidx >> 6, j = cidx & 63;
            float4 val = xsrc[cidx];
            xsl[rl * 64 + (j ^ rl)] = val;
        }
    }
    const int cf0 = 2 * v, cf1 = 2 * v + 1;
    bf16x8 wf0[8], wf1[8];
#pragma unroll
    for (int kk = 0; kk < 8; ++kk) {
        wf0[kk] = *(const bf16x8*)(Wt + (size_t)(cf0 * 16 + c16) * 256 + kk * 32 + kg * 8);
        wf1[kk] = *(const bf16x8*)(Wt + (size_t)(cf1 * 16 + c16) * 256 + kk * 32 + kg * 8);
    }
    __syncthreads();

    f32x4 acc0 = {}, acc1 = {};
#pragma unroll
    for (int kk = 0; kk < 8; ++kk) {
        int j0 = kk * 8 + kg * 2;
        float4 a0 = *(const float4*)(xs + (size_t)(c16 * 64 + (j0 ^ c16)) * 4);
        float4 a1 = *(const float4*)(xs + (size_t)(c16 * 64 + ((j0 + 1) ^ c16)) * 4);
        float fv[8] = {a0.x, a0.y, a0.z, a0.w, a1.x, a1.y, a1.z, a1.w};
        bf16x8 ahi, alo;
#pragma unroll
        for (int q = 0; q < 8; ++q) {
            unsigned u = __float_as_uint(fv[q]);
            float hval = __uint_as_float(u & 0xffff0000u);
            float d = fv[q] - hval;
            ahi[q] = (short)(u >> 16);
            alo[q] = (short)(__float_as_uint(d) >> 16);
        }
        acc0 = __builtin_amdgcn_mfma_f32_16x16x32_bf16(alo, wf0[kk], acc0, 0, 0, 0);
        acc0 = __builtin_amdgcn_mfma_f32_16x16x32_bf16(ahi, wf0[kk], acc0, 0, 0, 0);
        acc1 = __builtin_amdgcn_mfma_f32_16x16x32_bf16(alo, wf1[kk], acc1, 0, 0, 0);
        acc1 = __builtin_amdgcn_mfma_f32_16x16x32_bf16(ahi, wf1[kk], acc1, 0, 0, 0);
    }
#pragma unroll
    for (int i = 0; i < 4; ++i) {
        int row = r0 + kg * 4 + i;
        unsigned pu = (unsigned)f2bf(acc0[i]) | ((unsigned)f2bf(acc1[i]) << 16);
        h_p[(size_t)row * 64 + v * 16 + c16] = pu;
    }
    float ws0 = att_src[cf0 * 16 + c16], ws1 = att_src[cf1 * 16 + c16];
    float wd0 = att_dst[cf0 * 16 + c16], wd1 = att_dst[cf1 * 16 + c16];
    float pas[4], pad[4];
#pragma unroll
    for (int i = 0; i < 4; ++i) {
        pas[i] = acc0[i] * ws0 + acc1[i] * ws1;
        pad[i] = acc0[i] * wd0 + acc1[i] * wd1;
    }
#pragma unroll
    for (int m = 1; m < 16; m <<= 1) {
#pragma unroll
        for (int i = 0; i < 4; ++i) {
            pas[i] += __shfl_xor(pas[i], m, 64);
            pad[i] += __shfl_xor(pad[i], m, 64);
        }
    }
    const int head = v >> 1;
    if (c16 == 0) {
#pragma unroll
        for (int i = 0; i < 4; ++i) {
            atomicAdd(&sAs[(kg * 4 + i) * 2 + head], pas[i]);
            atomicAdd(&sAd[(kg * 4 + i) * 2 + head], pad[i]);
        }
    }
    __syncthreads();
    if (t < 32) {
        int row = t >> 1, hd = t & 1;
        as_[(r0 + row) * 2 + hd] = sAs[row * 2 + hd];
        ad_[(r0 + row) * 2 + hd] = sAd[row * 2 + hd];
    }
}

// ---------------- merged: per-node degree + block partial sum ----------------
__global__ void k_tot_part(const int* __restrict__ bcnt, int* __restrict__ tot,
                           int* __restrict__ part) {
    __shared__ int sd[256];
    int n = blockIdx.x * 256 + threadIdx.x;
    int s = 0;
    if (n < N_NODES) {
        int g = n / NPG, ln = n - g * NPG;
        const int* col = bcnt + (size_t)g * NBB * NPG + ln;
#pragma unroll
        for (int bi = 0; bi < NBB; ++bi) s += col[bi * NPG];
        tot[n] = s;
    }
    sd[threadIdx.x] = s;
    __syncthreads();
    for (int off = 128; off > 0; off >>= 1) {
        if (threadIdx.x < off) sd[threadIdx.x] += sd[threadIdx.x + off];
        __syncthreads();
    }
    if (threadIdx.x == 0) part[blockIdx.x] = sd[0];
}

// merged: base reduction + local scan + per-slice base expansion
__global__ void k_scan_base(const int* __restrict__ tot, const int* __restrict__ part,
                            const int* __restrict__ bcnt, int* __restrict__ offs,
                            int* __restrict__ base) {
    __shared__ int sp[256];
    __shared__ int sd[256];
    const int t = threadIdx.x;
    int pv = (t < NBLK && t < (int)blockIdx.x) ? part[t] : 0;
    sp[t] = pv;
    __syncthreads();
    for (int off = 128; off > 0; off >>= 1) {
        if (t < off) sp[t] += sp[t + off];
        __syncthreads();
    }
    const int bb = sp[0];
    __syncthreads();
    int i = blockIdx.x * 256 + t;
    int v = (i < N_NODES) ? tot[i] : 0;
    sd[t] = v;
    __syncthreads();
    for (int off = 1; off < 256; off <<= 1) {
        int u = (t >= off) ? sd[t - off] : 0;
        __syncthreads();
        sd[t] += u;
        __syncthreads();
    }
    if (i < N_NODES) {
        int o = bb + sd[t] - v;
        offs[i] = o;
        if (i == N_NODES - 1) offs[N_NODES] = o + v;
        int g = i / NPG, ln = i - g * NPG;
        const int* col = bcnt + (size_t)g * NBB * NPG + ln;
        int* bcol = base + (size_t)g * NBB * NPG + ln;
        int run = o;
#pragma unroll
        for (int bi = 0; bi < NBB; ++bi) {
            bcol[bi * NPG] = run;
            run += col[bi * NPG];
        }
    }
}

// scatter via LDS counters — no global atomics; payload = 4B (src only)
__global__ __launch_bounds__(256) void k_scatter(const int* __restrict__ src,
                                                 const int* __restrict__ dst,
                                                 const int* __restrict__ base,
                                                 int* __restrict__ csr) {
    __shared__ int cnt[NPG];
    const int g  = blockIdx.x & 7;
    const int bi = blockIdx.x >> 3;
    const int lo = g * NPG, hi = lo + NPG;
    const int* brow = base + (size_t)(g * NBB + bi) * NPG;
    for (int j = threadIdx.x; j < NPG; j += 256) cnt[j] = brow[j];
    __syncthreads();
    const int4* d4 = (const int4*)dst + bi * 6250;
    const int4* s4 = (const int4*)src + bi * 6250;
#pragma unroll 1
    for (int it = 0; it < 25; ++it) {
        int idx = it * 256 + threadIdx.x;
        if (idx < 6250) {
            int4 d = d4[idx];
            int4 s = s4[idx];
            if (d.x >= lo && d.x < hi) { int p = atomicAdd(&cnt[d.x - lo], 1); csr[p] = s.x; }
            if (d.y >= lo && d.y < hi) { int p = atomicAdd(&cnt[d.y - lo], 1); csr[p] = s.y; }
            if (d.z >= lo && d.z < hi) { int p = atomicAdd(&cnt[d.z - lo], 1); csr[p] = s.z; }
            if (d.w >= lo && d.w < hi) { int p = atomicAdd(&cnt[d.w - lo], 1); csr[p] = s.w; }
        }
    }
}

// ---------------- k_agg_uv: static aggregate (4 nodes/wave) + fused uv GEMM via LDS ----------------
__global__ __launch_bounds__(256) void k_agg_uv(const unsigned* __restrict__ h_p,
                                                const float* __restrict__ as_,
                                                const float* __restrict__ ad_,
                                                const int* __restrict__ offs,
                                                const int* __restrict__ csr,
                                                const float* __restrict__ conv_bias,
                                                const unsigned short* __restrict__ fc1t,
                                                const float* __restrict__ scale,
                                                const float* __restrict__ cc,
                                                unsigned* __restrict__ ab_p) {
    __shared__ unsigned lds_h2[16 * 68];   // 4352 B
    const int t    = threadIdx.x;
    const int v    = t >> 6;
    const int lane = t & 63;
    const int ql   = lane & 15;
    const int q    = lane >> 4;
    const int hd   = ql >> 3;
    const int nbase = blockIdx.x * 16;
    const uint4* h4 = (const uint4*)h_p;

#pragma unroll 1
    for (int j = 0; j < 4; ++j) {
        const int ln = v * 4 + j;
        const int n  = nbase + ln;
        const float adn = ad_[n * 2 + hd];
        float a[8] = {};
        float accw = 0.f;
        const int beg = offs[n], end = offs[n + 1];
        int i = beg + q;
        for (; i + 4 < end; i += 8) {
            int s0 = csr[i];
            int s1 = csr[i + 4];
            uint4 u0 = h4[(unsigned)(s0 * 16 + ql)];
            uint4 u1 = h4[(unsigned)(s1 * 16 + ql)];
            float l0 = as_[s0 * 2 + hd] + adn;
            float l1 = as_[s1 * 2 + hd] + adn;
            l0 = fmaxf(l0, 0.2f * l0);
            l1 = fmaxf(l1, 0.2f * l1);
            float w0 = __expf(l0), w1 = __expf(l1);
            float2 tt;
            tt = bf2(u0.x); a[0] += w0 * tt.x; a[1] += w0 * tt.y;
            tt = bf2(u0.y); a[2] += w0 * tt.x; a[3] += w0 * tt.y;
            tt = bf2(u0.z); a[4] += w0 * tt.x; a[5] += w0 * tt.y;
            tt = bf2(u0.w); a[6] += w0 * tt.x; a[7] += w0 * tt.y;
            tt = bf2(u1.x); a[0] += w1 * tt.x; a[1] += w1 * tt.y;
            tt = bf2(u1.y); a[2] += w1 * tt.x; a[3] += w1 * tt.y;
            tt = bf2(u1.z); a[4] += w1 * tt.x; a[5] += w1 * tt.y;
            tt = bf2(u1.w); a[6] += w1 * tt.x; a[7] += w1 * tt.y;
            accw += w0 + w1;
        }
        if (i < end) {
            int s0 = csr[i];
            uint4 u0 = h4[(unsigned)(s0 * 16 + ql)];
            float l0 = as_[s0 * 2 + hd] + adn;
            l0 = fmaxf(l0, 0.2f * l0);
            float w0 = __expf(l0);
            float2 tt;
            tt = bf2(u0.x); a[0] += w0 * tt.x; a[1] += w0 * tt.y;
            tt = bf2(u0.y); a[2] += w0 * tt.x; a[3] += w0 * tt.y;
            tt = bf2(u0.z); a[4] += w0 * tt.x; a[5] += w0 * tt.y;
            tt = bf2(u0.w); a[6] += w0 * tt.x; a[7] += w0 * tt.y;
            accw += w0;
        }
#pragma unroll
        for (int m = 16; m < 64; m <<= 1) {
#pragma unroll
            for (int jj = 0; jj < 8; ++jj) a[jj] += __shfl_xor(a[jj], m, 64);
            accw += __shfl_xor(accw, m, 64);
        }
        if (q == 0) {
            float es = as_[n * 2 + hd] + adn;   // self-loop
            es = fmaxf(es, 0.2f * es);
            float wsl = __expf(es);
            uint4 un = h4[(unsigned)(n * 16 + ql)];
            float2 tt;
            tt = bf2(un.x); a[0] += wsl * tt.x; a[1] += wsl * tt.y;
            tt = bf2(un.y); a[2] += wsl * tt.x; a[3] += wsl * tt.y;
            tt = bf2(un.z); a[4] += wsl * tt.x; a[5] += wsl * tt.y;
            tt = bf2(un.w); a[6] += wsl * tt.x; a[7] += wsl * tt.y;
            accw += wsl;
            float rinv = 1.f / accw;
            unsigned pw[4];
#pragma unroll
            for (int jj = 0; jj < 4; ++jj) {
                int w = 4 * ql + jj;
                int c = 32 * (w >> 4) + (w & 15);
                float o0 = a[2 * jj] * rinv + conv_bias[c];
                float o1 = a[2 * jj + 1] * rinv + conv_bias[c + 16];
                o0 = fmaxf(o0, 0.01f * o0);
                o1 = fmaxf(o1, 0.01f * o1);
                pw[jj] = (unsigned)f2bf(o0) | ((unsigned)f2bf(o1) << 16);
            }
            *(uint4*)&lds_h2[ln * 68 + ql * 4] = make_uint4(pw[0], pw[1], pw[2], pw[3]);
        }
    }
    __syncthreads();

    // ---- fused uv GEMM: wave v owns cf pair {2v, 2v+1}, A from LDS ----
    const int c16 = lane & 15;
    const int kg  = lane >> 4;
    const int cf0 = 2 * v, cf1 = 2 * v + 1;
    bf16x8 af[4];
#pragma unroll
    for (int kk = 0; kk < 4; ++kk)
        af[kk] = *(const bf16x8*)&lds_h2[c16 * 68 + kk * 16 + kg * 4];
    f32x4 acc0 = {}, acc1 = {};
#pragma unroll
    for (int kk = 0; kk < 4; ++kk) {
        bf16x8 b0 = *(const bf16x8*)(fc1t + (size_t)(cf0 * 16 + c16) * HC + kk * 32 + kg * 8);
        bf16x8 b1 = *(const bf16x8*)(fc1t + (size_t)(cf1 * 16 + c16) * HC + kk * 32 + kg * 8);
        acc0 = __builtin_amdgcn_mfma_f32_16x16x32_bf16(af[kk], b0, acc0, 0, 0, 0);
        acc1 = __builtin_amdgcn_mfma_f32_16x16x32_bf16(af[kk], b1, acc1, 0, 0, 0);
    }
    const int j0 = cf0 * 16 + c16, j1 = j0 + 16;
    const float s0 = scale[j0], s1 = scale[j1];
    const float q0 = cc[j0],    q1 = cc[j1];
#pragma unroll
    for (int i = 0; i < 4; ++i) {
        int row = nbase + kg * 4 + i;
        unsigned pu = (unsigned)f2bf(acc0[i] * s0 + q0)
                    | ((unsigned)f2bf(acc1[i] * s1 + q1) << 16);
        ab_p[(size_t)row * 64 + v * 16 + c16] = pu;
    }
}

// ---------------- k_edge: edge-order MFMA tail — coalesced out writes ----------------
__device__ __forceinline__ void mk_afrag2(uint4 ua, uint4 ub, bf16x8& ap) {
    float2 a, b; float z;
    a = bf2(ua.x); b = bf2(ub.x);
    z = a.x + b.x; z = fmaxf(z, 0.01f * z); ap[0] = f2bf_s(z);
    z = a.y + b.y; z = fmaxf(z, 0.01f * z); ap[1] = f2bf_s(z);
    a = bf2(ua.y); b = bf2(ub.y);
    z = a.x + b.x; z = fmaxf(z, 0.01f * z); ap[2] = f2bf_s(z);
    z = a.y + b.y; z = fmaxf(z, 0.01f * z); ap[3] = f2bf_s(z);
    a = bf2(ua.z); b = bf2(ub.z);
    z = a.x + b.x; z = fmaxf(z, 0.01f * z); ap[4] = f2bf_s(z);
    z = a.y + b.y; z = fmaxf(z, 0.01f * z); ap[5] = f2bf_s(z);
    a = bf2(ua.w); b = bf2(ub.w);
    z = a.x + b.x; z = fmaxf(z, 0.01f * z); ap[6] = f2bf_s(z);
    z = a.y + b.y; z = fmaxf(z, 0.01f * z); ap[7] = f2bf_s(z);
}

__global__ __launch_bounds__(256) void k_edge(const int* __restrict__ src,
                                              const int* __restrict__ dst,
                                              const unsigned* __restrict__ ab_p,
                                              const unsigned short* __restrict__ fc2m,
                                              const float* __restrict__ fc2_b,
                                              float* __restrict__ out) {
    const int wid  = blockIdx.x * 4 + (threadIdx.x >> 6);   // 50000 waves, 16 edges each
    const int lane = threadIdx.x & 63;
    const int c16  = lane & 15;
    const int kg   = lane >> 4;
    const int e0   = wid * 16;
    const int e    = e0 + c16;     // this lane's A-row edge
    bf16x8 bfr0 = *(const bf16x8*)(fc2m + (size_t)lane * 8);
    bf16x8 bfr1 = *(const bf16x8*)(fc2m + (size_t)(64 + lane) * 8);
    const uint4* abv = (const uint4*)ab_p;
    const int s = src[e], d = dst[e];
    uint4 ua0 = abv[(unsigned)(s * 16 + kg)];
    uint4 ua1 = abv[(unsigned)(s * 16 + 4 + kg)];
    uint4 ub0 = abv[(unsigned)(d * 16 + 8 + kg)];
    uint4 ub1 = abv[(unsigned)(d * 16 + 12 + kg)];
    bf16x8 ap0, ap1;
    mk_afrag2(ua0, ub0, ap0);
    mk_afrag2(ua1, ub1, ap1);
    f32x4 acc = {};
    acc = __builtin_amdgcn_mfma_f32_16x16x32_bf16(ap0, bfr0, acc, 0, 0, 0);
    acc = __builtin_amdgcn_mfma_f32_16x16x32_bf16(ap1, bfr1, acc, 0, 0, 0);
    if (c16 < 3) {
        const float ob = fc2_b[c16];
#pragma unroll
        for (int i = 0; i < 4; ++i)
            out[(size_t)(e0 + kg * 4 + i) * 3 + c16] = acc[i] + ob;
    }
}

extern "C" void kernel_launch(void* const* d_in, const int* in_sizes, int n_in,
                              void* d_out, int out_size, void* d_ws, size_t ws_size,
                              hipStream_t stream) {
    const float* x        = (const float*)d_in[0];
    const int*   ei       = (const int*)d_in[1];
    const float* W        = (const float*)d_in[2];
    const float* att_src  = (const float*)d_in[3];
    const float* att_dst  = (const float*)d_in[4];
    const float* conv_b   = (const float*)d_in[5];
    const float* fc1_w    = (const float*)d_in[6];
    const float* fc1_b    = (const float*)d_in[7];
    const float* gamma    = (const float*)d_in[8];
    const float* beta     = (const float*)d_in[9];
    const float* mean     = (const float*)d_in[10];
    const float* var      = (const float*)d_in[11];
    const float* fc2_w    = (const float*)d_in[12];
    const float* fc2_b    = (const float*)d_in[13];
    float*       out      = (float*)d_out;
    char*        ws       = (char*)d_ws;

    const int* src = ei;
    const int* dst = ei + N_EDGES;

    unsigned*       h_p   = (unsigned*)(ws + OFF_HBF);
    unsigned*       ab_p  = (unsigned*)(ws + OFF_AB);
    float*          as_   = (float*)(ws + OFF_AS);
    float*          ad_   = (float*)(ws + OFF_AD);
    int*            offs  = (int*)(ws + OFF_OFFS);
    int*            tot   = (int*)(ws + OFF_TOT);
    int*            part  = (int*)(ws + OFF_PART);
    int*            csr   = (int*)(ws + OFF_CSR);
    unsigned short* Wt    = (unsigned short*)(ws + OFF_WT);
    unsigned short* fc1t  = (unsigned short*)(ws + OFF_FC1T);
    float*          scale = (float*)(ws + OFF_SCALE);
    float*          cc    = (float*)(ws + OFF_CC);
    unsigned short* fc2m  = (unsigned short*)(ws + OFF_FC2M);
    int*            bcnt  = (int*)(ws + OFF_BCNT);
    int*            base  = (int*)(ws + OFF_BASE);

    // prep first (produces Wt consumed by k_front's xw branch)
    k_prep<<<235, 256, 0, stream>>>(W, fc1_w, fc1_b, gamma, beta, mean, var, fc2_w,
                                    Wt, fc1t, scale, cc, fc2m);

    // fused histogram (blocks 0..255, launched first) + xw-GEMM
    k_front<<<HIST_BLOCKS + XW_BLOCKS, 256, 0, stream>>>(x, Wt, att_src, att_dst,
                                                         h_p, as_, ad_, dst, bcnt);

    // CSR finish
    k_tot_part <<<NBLK, 256, 0, stream>>>(bcnt, tot, part);
    k_scan_base<<<NBLK, 256, 0, stream>>>(tot, part, bcnt, offs, base);
    k_scatter  <<<8 * NBB, 256, 0, stream>>>(src, dst, base, csr);

    // aggregate + fused uv GEMM, then edge-order tail
    k_agg_uv<<<N_NODES / 16, 256, 0, stream>>>(h_p, as_, ad_, offs, csr, conv_b,
                                               fc1t, scale, cc, ab_p);
    k_edge  <<<N_EDGES / 64, 256, 0, stream>>>(src, dst, ab_p, fc2m, fc2_b, out);
}